// Round 1
// baseline (55.627 us; speedup 1.0000x reference)
//
#include <hip/hip_runtime.h>
#include <math.h>

// Problem constants from the reference: B=8, C=3, H=64, W=64.
#define BB 8
#define CC 3
#define HH 64
#define WW 64
#define NN (HH * WW)
#define IMG_FLOATS (CC * NN)   // 12288 floats = 48 KB

// The reference's dense tent-weight einsum is exactly 4-tap bilinear
// interpolation with zero padding (tent(d)=relu(1-|d|), support width 2).
//
// R3 changes vs R2 (latency-focused; caches are COLD each timed iteration
// because the harness's 268 MB poison fill wipes L2+L3):
//  - 256 blocks x 128 threads: all 256 CUs active (was 128 blocks).
//  - whole image (48 KB) staged to LDS via global_load_lds width=16,
//    issued BEFORE the theta-dependent chain -> one coalesced streaming
//    HBM fetch that overlaps sincos/index math, instead of 12 scattered
//    cold 4B loads per thread on the critical path.
//  - 16B-chunk XOR swizzle (slot ^= row&15) applied to BOTH the global
//    source addresses (LDS dest stays linear, as global_load_lds requires)
//    and the LDS read indices. Kills the 32-way bank degeneracy of tap
//    reads at |sin(theta)| ~ 1 (lane address stride 256 B -> bank stride 0);
//    worst case drops to <=8-way.
__global__ __launch_bounds__(128) void rot_bilinear_kernel(
        const float* __restrict__ theta,   // [B,1]
        const float* __restrict__ image,   // [C,H,W]
        float* __restrict__ out) {         // [B,C,H,W]
    __shared__ float simg[IMG_FLOATS];     // 48 KB, swizzled layout

    const int t    = threadIdx.x;          // 0..127
    const int wv   = t >> 6;               // wave id (0/1)
    const int lane = t & 63;

    // ---- stage 48 KB: 24 issues/wave x 2 waves x 1 KB ----
    // dest float index d is linear; source is pre-swizzled so that
    // LDS[chunk (r<<4)|slot] == image[chunk (r<<4)|(slot^(r&15))]
    // (involution: read side applies the same XOR).
    #pragma unroll
    for (int it = 0; it < 24; ++it) {
        int d     = it * 512 + wv * 256 + lane * 4;   // dest float idx
        int chunk = d >> 2;
        int r     = chunk >> 4;                       // global row 0..191
        int slot  = chunk & 15;
        int sfl   = ((r << 4) | (slot ^ (r & 15))) << 2;  // source float idx
        __builtin_amdgcn_global_load_lds(
            (const __attribute__((address_space(1))) void*)(image + sfl),
            (__attribute__((address_space(3))) void*)(simg + it * 512 + wv * 256),
            16, 0, 0);
    }

    // ---- theta-dependent chain: overlaps the in-flight staging fetch ----
    const int bid = blockIdx.x;
    const int b   = bid >> 5;                  // uniform per block -> s_load
    const int n   = ((bid & 31) << 7) + t;     // pixel 0..4095 within batch
    const int gy  = n >> 6;
    const int gx  = n & (WW - 1);

    const float c_x = (WW - 1) * 0.5f;
    const float c_y = (HH - 1) * 0.5f;

    float th = theta[b];
    float s, c;
    __sincosf(th, &s, &c);   // hw v_sin/v_cos; theta ~ N(0,1): ample margin

    float x_rel = (float)gx - c_x;
    float y_rel = (float)gy - c_y;
    float src_x = fmaf(c, x_rel, fmaf(s, y_rel, c_x));
    float src_y = fmaf(-s, x_rel, fmaf(c, y_rel, c_y));

    float fx = floorf(src_x);
    float fy = floorf(src_y);
    int x0 = (int)fx;
    int y0 = (int)fy;
    float ax = src_x - fx;       // weight of x0+1
    float ay = src_y - fy;       // weight of y0+1
    float bx = 1.0f - ax;
    float by = 1.0f - ay;

    // Zero-padding: out-of-range taps get weight 0; indices clamped so the
    // LDS reads are always in-bounds (value then multiplied by 0).
    bool vx0 = (unsigned)x0       < (unsigned)WW;
    bool vx1 = (unsigned)(x0 + 1) < (unsigned)WW;
    bool vy0 = (unsigned)y0       < (unsigned)HH;
    bool vy1 = (unsigned)(y0 + 1) < (unsigned)HH;
    float wx0 = vx0 ? bx : 0.0f;
    float wx1 = vx1 ? ax : 0.0f;
    float wy0 = vy0 ? by : 0.0f;
    float wy1 = vy1 ? ay : 0.0f;
    float w00 = wy0 * wx0;
    float w01 = wy0 * wx1;
    float w10 = wy1 * wx0;
    float w11 = wy1 * wx1;

    int x0c = min(max(x0, 0), WW - 1);
    int x1c = min(max(x0 + 1, 0), WW - 1);
    int y0c = min(max(y0, 0), HH - 1);
    int y1c = min(max(y0 + 1, 0), HH - 1);

    // Swizzled LDS indices (must mirror the staging swizzle).
    // Within a channel: idx = (y<<6) | ((slot ^ (y&15))<<2) | (x&3);
    // channel offset ch*4096 is a multiple of 64 rows, so y&15 == r&15.
    int m0 = y0c & 15, m1 = y1c & 15;
    int s0 = x0c >> 2, s1 = x1c >> 2;
    int i00 = (y0c << 6) | ((s0 ^ m0) << 2) | (x0c & 3);
    int i01 = (y0c << 6) | ((s1 ^ m0) << 2) | (x1c & 3);
    int i10 = (y1c << 6) | ((s0 ^ m1) << 2) | (x0c & 3);
    int i11 = (y1c << 6) | ((s1 ^ m1) << 2) | (x1c & 3);

    __syncthreads();   // compiler emits s_waitcnt vmcnt(0) first: staging done

    const float* sc = simg;
    float* o = out + b * (CC * NN) + n;
    #pragma unroll
    for (int ch = 0; ch < CC; ++ch, sc += NN, o += NN) {
        float v = w00 * sc[i00] + w01 * sc[i01]
                + w10 * sc[i10] + w11 * sc[i11];
        *o = v;          // wave writes 64 contiguous floats: coalesced
    }
}

extern "C" void kernel_launch(void* const* d_in, const int* in_sizes, int n_in,
                              void* d_out, int out_size, void* d_ws, size_t ws_size,
                              hipStream_t stream) {
    const float* theta = (const float*)d_in[0];  // [B,1] fp32
    const float* image = (const float*)d_in[1];  // [C,H,W] fp32
    float* out = (float*)d_out;                  // [B,C,H,W] fp32

    const int block = 128;                       // 2 waves/block
    const int grid  = 256;                       // 8 batches x 32 blocks: all CUs
    rot_bilinear_kernel<<<grid, block, 0, stream>>>(theta, image, out);
}